// Round 10
// baseline (7893.080 us; speedup 1.0000x reference)
//
#include <hip/hip_runtime.h>
#include <math.h>

#define N 512
#define NITERS 100
#define SC 10.0f

// round-to-nearest-even fp32 -> bf16 pair packed into one uint
__device__ __forceinline__ unsigned int pack_bf16(float a, float b) {
    unsigned int ua = __float_as_uint(a);
    unsigned int ub = __float_as_uint(b);
    ua = (ua + 0x7fffu + ((ua >> 16) & 1u)) >> 16;
    ub = (ub + 0x7fffu + ((ub >> 16) & 1u)) >> 16;
    return ua | (ub << 16);
}

// s = dot of this lane's 8 bf16 elements with w (8 cols owned by lane)
__device__ __forceinline__ float rowdot(uint4 q, float4 w0, float4 w1) {
    float f0 = __uint_as_float(q.x << 16);
    float f1 = __uint_as_float(q.x & 0xffff0000u);
    float f2 = __uint_as_float(q.y << 16);
    float f3 = __uint_as_float(q.y & 0xffff0000u);
    float f4 = __uint_as_float(q.z << 16);
    float f5 = __uint_as_float(q.z & 0xffff0000u);
    float f6 = __uint_as_float(q.w << 16);
    float f7 = __uint_as_float(q.w & 0xffff0000u);
    float sa = f0 * w0.x;
    sa = fmaf(f2, w0.z, sa);
    sa = fmaf(f4, w1.x, sa);
    sa = fmaf(f6, w1.z, sa);
    float sb = f1 * w0.y;
    sb = fmaf(f3, w0.w, sb);
    sb = fmaf(f5, w1.y, sb);
    sb = fmaf(f7, w1.w, sb);
    return sa + sb;
}

// t_j += K_ij * r for this lane's 8 columns
__device__ __forceinline__ void tacc(uint4 q, float r,
        float& t0, float& t1, float& t2, float& t3,
        float& t4, float& t5, float& t6, float& t7) {
    t0 = fmaf(__uint_as_float(q.x << 16),         r, t0);
    t1 = fmaf(__uint_as_float(q.x & 0xffff0000u), r, t1);
    t2 = fmaf(__uint_as_float(q.y << 16),         r, t2);
    t3 = fmaf(__uint_as_float(q.y & 0xffff0000u), r, t3);
    t4 = fmaf(__uint_as_float(q.z << 16),         r, t4);
    t5 = fmaf(__uint_as_float(q.z & 0xffff0000u), r, t5);
    t6 = fmaf(__uint_as_float(q.w << 16),         r, t6);
    t7 = fmaf(__uint_as_float(q.w & 0xffff0000u), r, t7);
}

#define LD4(p, k) (((const uint4*)((p) + (size_t)(k) * RS))[lane])
#define PRE4(S, p) \
    S##0 = LD4(p, 0); S##1 = LD4(p, 1); S##2 = LD4(p, 2); S##3 = LD4(p, 3);

// fused batch of 4 rows: 4 rowdots, 4 interleaved butterfly chains,
// 4 rcp, 4 taccs -- all state in named scalars (64-VGPR budget, rounds 5-9)
#define BATCH4(Q0, Q1, Q2, Q3, bidx) { \
    float s0 = rowdot(Q0, w0, w1), s1 = rowdot(Q1, w0, w1); \
    float s2 = rowdot(Q2, w0, w1), s3 = rowdot(Q3, w0, w1); \
    _Pragma("unroll") \
    for (int o = 32; o > 0; o >>= 1) { \
        s0 += __shfl_xor(s0, o, 64); s1 += __shfl_xor(s1, o, 64); \
        s2 += __shfl_xor(s2, o, 64); s3 += __shfl_xor(s3, o, 64); \
    } \
    if (last && lane == 0) { \
        lnS_s[wave + 16 * (4 * (bidx) + 0)] = __logf(s0); \
        lnS_s[wave + 16 * (4 * (bidx) + 1)] = __logf(s1); \
        lnS_s[wave + 16 * (4 * (bidx) + 2)] = __logf(s2); \
        lnS_s[wave + 16 * (4 * (bidx) + 3)] = __logf(s3); \
    } \
    s0 = __builtin_amdgcn_rcpf(s0); s1 = __builtin_amdgcn_rcpf(s1); \
    s2 = __builtin_amdgcn_rcpf(s2); s3 = __builtin_amdgcn_rcpf(s3); \
    tacc(Q0, s0, t0, t1, t2, t3, t4, t5, t6, t7); \
    tacc(Q1, s1, t0, t1, t2, t3, t4, t5, t6, t7); \
    tacc(Q2, s2, t0, t1, t2, t3, t4, t5, t6, t7); \
    tacc(Q3, s3, t0, t1, t2, t3, t4, t5, t6, t7); \
}

// One block (1024 thr, 16 waves) per matrix. Fused multiplicative Sinkhorn
// on precomputed bf16 K' = exp(A*SC - rowmax_i) (row-major only, read ONCE
// per iteration -- lowest possible traffic):
//   s_i = sum_j K_ij w_j (dot, shuffle-reduce); r_i = 1/s_i;
//   t_j = sum_i K_ij r_i (axpy, register reuse); w_j = 1/t_j.
// Batch-4 double-buffered: 8 uint4 in flight + 4 interleaved shuffle chains,
// ~58 VGPR -- fits the 64-VGPR budget the allocator enforces (rounds 5-9).
// LDS padded >80KB: forces the backend's occupancy model to 1 WG/CU =
// 4 waves/EU, which (opportunistically) lifts the VGPR budget to 128.
__global__ __launch_bounds__(1024) __attribute__((amdgpu_waves_per_eu(4, 4)))
void sinkhorn_fused4(const float* __restrict__ X, float* __restrict__ P) {
    __shared__ float w_s[N], m_s[N], lnS_s[N];
    __shared__ float c_lds[16 * N];        // per-wave t partials (32 KB)
    __shared__ float pad_lds[12 * 1024];   // 48 KB occupancy pad (see above)

    const int tid  = threadIdx.x;
    const int lane = tid & 63;
    const int wave = tid >> 6;          // 0..15

    const size_t base = (size_t)blockIdx.x * N * N;
    const float* __restrict__ A   = X + base;
    float*       __restrict__ out = P + base;
    unsigned short* __restrict__ Kb = (unsigned short*)(P + base);  // 512 KB own region

    if (tid < N) w_s[tid] = 1.0f;

    // ---- pass 0: K = exp(A*SC - rowmax) bf16 row-major; rowmax -> m_s ----
    #pragma unroll 1
    for (int r = wave; r < N; r += 16) {
        const float4* rowp = (const float4*)(A + (size_t)r * N);
        float4 a0 = rowp[lane];          // cols 4L..4L+3
        float4 a1 = rowp[lane + 64];     // cols 256+4L..
        float x0 = a0.x*SC, x1 = a0.y*SC, x2 = a0.z*SC, x3 = a0.w*SC;
        float x4 = a1.x*SC, x5 = a1.y*SC, x6 = a1.z*SC, x7 = a1.w*SC;
        float mx = fmaxf(fmaxf(fmaxf(x0,x1), fmaxf(x2,x3)),
                         fmaxf(fmaxf(x4,x5), fmaxf(x6,x7)));
        #pragma unroll
        for (int o = 32; o > 0; o >>= 1) mx = fmaxf(mx, __shfl_xor(mx, o, 64));
        uint2 p0, p1;
        p0.x = pack_bf16(__expf(x0 - mx), __expf(x1 - mx));
        p0.y = pack_bf16(__expf(x2 - mx), __expf(x3 - mx));
        p1.x = pack_bf16(__expf(x4 - mx), __expf(x5 - mx));
        p1.y = pack_bf16(__expf(x6 - mx), __expf(x7 - mx));
        uint2* krow = (uint2*)(Kb + (size_t)r * N);
        krow[lane]      = p0;
        krow[lane + 64] = p1;
        if (lane == 0) m_s[r] = mx;
    }
    __threadfence();     // own global K writes visible before re-reads
    __syncthreads();

    // ---- 100 fused iterations, K read exactly once each ----
    const size_t RS = (size_t)16 * N;   // ushorts between this wave's rows
    for (int it = 0; it < NITERS; ++it) {
        const bool last = (it == NITERS - 1);
        const float4 w0 = *(const float4*)(w_s + 8 * lane);      // cols 8L..8L+3
        const float4 w1 = *(const float4*)(w_s + 8 * lane + 4);  // cols 8L+4..8L+7
        float t0=0.f,t1=0.f,t2=0.f,t3=0.f,t4=0.f,t5=0.f,t6=0.f,t7=0.f;

        const unsigned short* kp = Kb + (size_t)wave * N;
        uint4 A0, A1, A2, A3, B0, B1, B2, B3;

        PRE4(A, kp)               // rows m = 0..3   (r = wave + 16*m)
        PRE4(B, kp + 4 * RS)      // m = 4..7
        BATCH4(A0, A1, A2, A3, 0)
        PRE4(A, kp + 8 * RS)      // m = 8..11
        BATCH4(B0, B1, B2, B3, 1)
        PRE4(B, kp + 12 * RS)     // m = 12..15
        BATCH4(A0, A1, A2, A3, 2)
        PRE4(A, kp + 16 * RS)     // m = 16..19
        BATCH4(B0, B1, B2, B3, 3)
        PRE4(B, kp + 20 * RS)     // m = 20..23
        BATCH4(A0, A1, A2, A3, 4)
        PRE4(A, kp + 24 * RS)     // m = 24..27
        BATCH4(B0, B1, B2, B3, 5)
        PRE4(B, kp + 28 * RS)     // m = 28..31
        BATCH4(A0, A1, A2, A3, 6)
        BATCH4(B0, B1, B2, B3, 7)

        // cross-wave t reduction
        *(float4*)(c_lds + wave * N + 8 * lane)     = make_float4(t0,t1,t2,t3);
        *(float4*)(c_lds + wave * N + 8 * lane + 4) = make_float4(t4,t5,t6,t7);
        __syncthreads();
        if (tid < N) {
            float ct = 0.f;
            #pragma unroll
            for (int w = 0; w < 16; ++w) ct += c_lds[w * N + tid];
            w_s[tid] = __builtin_amdgcn_rcpf(fmaxf(ct, 1e-38f));
        }
        __syncthreads();
    }

    // keep pad_lds materialized (data-dependent guard, never true in practice)
    if (__float_as_uint(A[0]) == 0xDEADBEEFu) {
        pad_lds[tid] = w_s[0];
        out[511] = pad_lds[1023 - tid];
    }

    // ---- epilogue: P = exp(A*SC - m_i - lnS_i + ln w_j) from fp32 A ----
    float* g_s  = c_lds;        // ln w  [N]
    float* rt_s = c_lds + N;    // -(m + lnS) [N]
    if (tid < N) {
        g_s[tid]  = __logf(w_s[tid]);
        rt_s[tid] = -(m_s[tid] + lnS_s[tid]);
    }
    __syncthreads();

    #pragma unroll 1
    for (int r = wave; r < N; r += 16) {
        const float rt = rt_s[r];
        const float4* rowp = (const float4*)(A + (size_t)r * N);
        float4 a0 = rowp[lane];
        float4 a1 = rowp[lane + 64];
        float4 g0 = *(const float4*)(g_s + 4 * lane);
        float4 g1 = *(const float4*)(g_s + 256 + 4 * lane);
        float4 o0, o1;
        o0.x = __expf(fmaf(a0.x, SC, rt) + g0.x);
        o0.y = __expf(fmaf(a0.y, SC, rt) + g0.y);
        o0.z = __expf(fmaf(a0.z, SC, rt) + g0.z);
        o0.w = __expf(fmaf(a0.w, SC, rt) + g0.w);
        o1.x = __expf(fmaf(a1.x, SC, rt) + g1.x);
        o1.y = __expf(fmaf(a1.y, SC, rt) + g1.y);
        o1.z = __expf(fmaf(a1.z, SC, rt) + g1.z);
        o1.w = __expf(fmaf(a1.w, SC, rt) + g1.w);
        float4* outp = (float4*)(out + (size_t)r * N);
        outp[lane]      = o0;
        outp[lane + 64] = o1;
    }
}

extern "C" void kernel_launch(void* const* d_in, const int* in_sizes, int n_in,
                              void* d_out, int out_size, void* d_ws, size_t ws_size,
                              hipStream_t stream) {
    const float* X = (const float*)d_in[0];
    float* P = (float*)d_out;
    const int batch = in_sizes[0] / (N * N);   // 128
    hipLaunchKernelGGL(sinkhorn_fused4, dim3(batch), dim3(1024), 0, stream, X, P);
}